// Round 1
// 921.348 us; speedup vs baseline: 1.0095x; 1.0095x over previous
//
#include <hip/hip_runtime.h>

// ---------------------------------------------------------------------------
// DrugCell-style VNN. R5: gemm_bt rewritten as 256x256 tile, BK=32, 8 waves
// (2Mx4N), 4-deep circular LDS buffer (128 KiB), counted s_waitcnt vmcnt(12)
// (never drain-to-0 in main loop), raw s_barrier (no __syncthreads drain).
// Liveness: stage(t+3) targets buf[(t+3)&3]; buffer overwritten at iter t+1
// is buf[t&3], dead after iter t's end barrier (lgkmcnt(0) precedes it).
// Term layers: grid.y bumped for TLP. Everything else unchanged from R4.
// ---------------------------------------------------------------------------

typedef float f32x4 __attribute__((ext_vector_type(4)));
typedef __bf16 bf16x8 __attribute__((ext_vector_type(8)));

#define GL2LDS(g, l)                                                          \
  __builtin_amdgcn_global_load_lds(                                           \
      (__attribute__((address_space(1))) void*)(g),                           \
      (__attribute__((address_space(3))) void*)(l), 16, 0, 0)

__device__ __forceinline__ unsigned short f2bf(float f) {
  unsigned int u = __float_as_uint(f);
  u = u + 0x7fffu + ((u >> 16) & 1u);   // round-to-nearest-even
  return (unsigned short)(u >> 16);
}

__device__ __forceinline__ float bf2f(unsigned int lo16) {
  return __uint_as_float(lo16 << 16);
}

__device__ __forceinline__ float tanh_fast(float x) {
  float e = __expf(2.0f * x);
  return 1.0f - __fdividef(2.0f, e + 1.0f);
}

// ---------------------------------------------------------------------------
// fp32 -> bf16 conversion of x and Wg in one launch
// ---------------------------------------------------------------------------
__global__ __launch_bounds__(256) void cvt_all(
    const float* __restrict__ x, const float* __restrict__ wg,
    unsigned short* __restrict__ xb, unsigned short* __restrict__ wgb) {
  constexpr int NX = 12320768 / 4;
  constexpr int NW = 49283072 / 4;
  int i = blockIdx.x * 256 + threadIdx.x;
  const float* src;
  unsigned short* dst;
  int j;
  if (i < NX) {
    src = x; dst = xb; j = i;
  } else {
    j = i - NX;
    if (j >= NW) return;
    src = wg; dst = wgb;
  }
  float4 v = ((const float4*)src)[j];
  ushort4 o;
  o.x = f2bf(v.x); o.y = f2bf(v.y); o.z = f2bf(v.z); o.w = f2bf(v.w);
  ((ushort4*)dst)[j] = o;
}

// ---------------------------------------------------------------------------
// bf16 GEMM: C(4096x16384) = A(MxK)*B(NxK)^T + bias[n], K=3008.
// 256x256 tile, BK=32 (94 K-tiles), 8 waves, 4-deep circular LDS pipeline.
// LDS per operand-tile: [128 super-rows][8 chunks of 16B], chunk ^= (sr&7).
// Read: row ra, k-chunk q(=lane quad) at byte (ra>>1)*128 +
//       ((((ra&1)<<2)|q) ^ ((ra>>1)&7))*16  -> uniform banks, conflict-free.
// Stage: linear LDS dest (tid*16 within 8KB call); inverse-swizzled global
//        source: sr=tid>>3, u=(tid&7)^(sr&7), row=2*sr+(u>>2), col8=(u&3)*8.
// ---------------------------------------------------------------------------
__global__ __launch_bounds__(512, 2) void gemm_bt(
    const unsigned short* __restrict__ A, const unsigned short* __restrict__ Bm,
    const float* __restrict__ bias, unsigned short* __restrict__ C) {
  constexpr int N = 16384, K = 3008;
  constexpr int NT = K / 32;                       // 94 K-tiles
  __shared__ unsigned short lds[65536];            // 128 KiB: A 4x16KB | B 4x16KB
  const int tid = threadIdx.x;
  const int w = tid >> 6, l = tid & 63;
  const int m0 = blockIdx.y * 256, n0 = blockIdx.x * 256;

  // ---- staging source (per-lane, pre-swizzled); call1 = call0 + 128 rows
  const int srt = tid >> 3;                        // 0..63
  const int u0 = (tid & 7) ^ (srt & 7);
  const int r0 = 2 * srt + (u0 >> 2);
  const int c0e = (u0 & 3) * 8;
  const unsigned short* gA0 = A + (size_t)(m0 + r0) * K + c0e;
  const unsigned short* gA1 = gA0 + (size_t)128 * K;
  const unsigned short* gB0 = Bm + (size_t)(n0 + r0) * K + c0e;
  const unsigned short* gB1 = gB0 + (size_t)128 * K;

#define STAGE(bufi, tt)                                                       \
  do {                                                                        \
    const int kofs_ = (tt) * 32;                                              \
    unsigned short* dA_ = lds + (bufi) * 8192 + w * 512;                      \
    unsigned short* dB_ = lds + 32768 + (bufi) * 8192 + w * 512;              \
    GL2LDS(gA0 + kofs_, dA_);                                                 \
    GL2LDS(gA1 + kofs_, dA_ + 4096);                                          \
    GL2LDS(gB0 + kofs_, dB_);                                                 \
    GL2LDS(gB1 + kofs_, dB_ + 4096);                                          \
  } while (0)

  // ---- per-thread fragment read offsets (loop-invariant, ushort units)
  const int quad = l >> 4;
  const int lrow = l & 15;
  const int wm = (w >> 2) * 128, wn = (w & 3) * 64;
  int aOff[8], bOff[4];
#pragma unroll
  for (int f = 0; f < 8; ++f) {
    int ra = wm + f * 16 + lrow;
    int sr = ra >> 1;
    int ch = (((ra & 1) << 2) | quad) ^ (sr & 7);
    aOff[f] = sr * 64 + ch * 8;
  }
#pragma unroll
  for (int nn = 0; nn < 4; ++nn) {
    int rb = wn + nn * 16 + lrow;
    int sr = rb >> 1;
    int ch = (((rb & 1) << 2) | quad) ^ (sr & 7);
    bOff[nn] = sr * 64 + ch * 8;
  }

  f32x4 acc[8][4];
#pragma unroll
  for (int f = 0; f < 8; ++f)
#pragma unroll
    for (int nn = 0; nn < 4; ++nn) acc[f][nn] = (f32x4)0.0f;

#define KTILE(t_, VMSTR, DOSTAGE)                                             \
  {                                                                           \
    if (DOSTAGE) STAGE(((t_) + 3) & 3, (t_) + 3);                             \
    asm volatile("s_waitcnt " VMSTR ::: "memory");                            \
    __builtin_amdgcn_s_barrier();                                             \
    __builtin_amdgcn_sched_barrier(0);                                        \
    const unsigned short* pa_ = lds + ((t_) & 3) * 8192;                      \
    const unsigned short* pb_ = lds + 32768 + ((t_) & 3) * 8192;              \
    bf16x8 av[8], bv[4];                                                      \
    _Pragma("unroll") for (int f = 0; f < 8; ++f)                             \
        av[f] = *(const bf16x8*)(pa_ + aOff[f]);                              \
    _Pragma("unroll") for (int nn = 0; nn < 4; ++nn)                          \
        bv[nn] = *(const bf16x8*)(pb_ + bOff[nn]);                            \
    __builtin_amdgcn_s_setprio(1);                                            \
    _Pragma("unroll") for (int f = 0; f < 8; ++f)                             \
      _Pragma("unroll") for (int nn = 0; nn < 4; ++nn)                        \
          acc[f][nn] = __builtin_amdgcn_mfma_f32_16x16x32_bf16(               \
              av[f], bv[nn], acc[f][nn], 0, 0, 0);                            \
    __builtin_amdgcn_s_setprio(0);                                            \
    asm volatile("s_waitcnt lgkmcnt(0)" ::: "memory");                        \
    __builtin_amdgcn_sched_barrier(0);                                        \
    __builtin_amdgcn_s_barrier();                                             \
  }

  // prologue: 3 tiles of lead (12 calls in flight)
  STAGE(0, 0);
  STAGE(1, 1);
  STAGE(2, 2);

  for (int t = 0; t < NT - 3; ++t) KTILE(t, "vmcnt(12)", true);
  KTILE(NT - 3, "vmcnt(8)", false);
  KTILE(NT - 2, "vmcnt(4)", false);
  KTILE(NT - 1, "vmcnt(0)", false);

#undef KTILE
#undef STAGE

  // epilogue: C/D layout col=lane&15, row=quad*4+reg (verified layout)
#pragma unroll
  for (int nn = 0; nn < 4; ++nn) {
    int n = n0 + wn + nn * 16 + lrow;
    float bn = bias[n];
#pragma unroll
    for (int f = 0; f < 8; ++f) {
      int mbase = m0 + wm + f * 16 + quad * 4;
#pragma unroll
      for (int r = 0; r < 4; ++r) {
        float v = acc[f][nn][r] + bn;
        C[(size_t)(mbase + r) * N + n] = f2bf(v);
      }
    }
  }
}

// ---------------------------------------------------------------------------
// row loaders (term-slice of IC elements)
// ---------------------------------------------------------------------------
template <int IC>
__device__ __forceinline__ void load_row(const unsigned short* p, float* d) {
  static_assert(IC % 8 == 0, "");
#pragma unroll
  for (int i = 0; i < IC / 8; ++i) {
    uint4 u = *(const uint4*)(p + i * 8);
    d[i * 8 + 0] = bf2f(u.x & 0xffffu); d[i * 8 + 1] = bf2f(u.x >> 16);
    d[i * 8 + 2] = bf2f(u.y & 0xffffu); d[i * 8 + 3] = bf2f(u.y >> 16);
    d[i * 8 + 4] = bf2f(u.z & 0xffffu); d[i * 8 + 5] = bf2f(u.z >> 16);
    d[i * 8 + 6] = bf2f(u.w & 0xffffu); d[i * 8 + 7] = bf2f(u.w >> 16);
  }
}
template <int IC>
__device__ __forceinline__ void load_row(const float* p, float* d) {
  static_assert(IC % 4 == 0, "");
#pragma unroll
  for (int i = 0; i < IC / 4; ++i) {
    float4 v = *(const float4*)(p + i * 4);
    d[i * 4 + 0] = v.x; d[i * 4 + 1] = v.y;
    d[i * 4 + 2] = v.z; d[i * 4 + 3] = v.w;
  }
}

// ---------------------------------------------------------------------------
// Term layer: block = TG terms x (4096/gridDim.y) b's; tid = bsub*TG + t.
// Wave lanes cover consecutive terms -> contiguous row-slice reads.
// ---------------------------------------------------------------------------
template <typename TIN, typename TOUT, int T, int IC, int TG, bool FIRST>
__global__ __launch_bounds__(256) void term_layer(
    const TIN* __restrict__ in, const float* __restrict__ prevStats,
    const float* __restrict__ prevGm, const float* __restrict__ prevBt,
    const float* __restrict__ W, const float* __restrict__ bvec,
    TOUT* __restrict__ out, float* __restrict__ curStats) {
  constexpr int WIN = T * IC;
  constexpr int WOUT = T * 6;
  constexpr int NB = 256 / TG;
  const int tb = blockIdx.x * TG;
  const int t = threadIdx.x & (TG - 1);
  const int bsub = threadIdx.x / TG;

  __shared__ float sW[TG * 6 * IC];
  __shared__ float sB[TG * 6];
  __shared__ float sScale[FIRST ? 1 : TG * IC];
  __shared__ float sShift[FIRST ? 1 : TG * IC];
  __shared__ float sRed[256][13];  // 13: odd stride, conflict-free

  for (int i = threadIdx.x; i < TG * 6 * IC; i += 256)
    sW[i] = W[(size_t)tb * 6 * IC + i];
  for (int i = threadIdx.x; i < TG * 6; i += 256) sB[i] = bvec[tb * 6 + i];
  if constexpr (!FIRST) {
    for (int i = threadIdx.x; i < TG * IC; i += 256) {
      int gc = tb * IC + i;
      float mu = prevStats[gc] * (1.0f / 4096.0f);
      float var = prevStats[WIN + gc] * (1.0f / 4096.0f) - mu * mu;
      float sc = rsqrtf(var + 1e-5f) * prevGm[gc];
      sScale[i] = sc;
      sShift[i] = prevBt[gc] - mu * sc;
    }
  }
  __syncthreads();

  float ls[6], lq[6];
#pragma unroll
  for (int i = 0; i < 6; ++i) { ls[i] = 0.0f; lq[i] = 0.0f; }

  const int bchunk = 4096 / gridDim.y;
  const int rows = bchunk / NB;
  const int b0 = blockIdx.y * bchunk + bsub * rows;
  for (int i = 0; i < rows; ++i) {
    int b = b0 + i;
    float child[IC];
    load_row<IC>(in + (size_t)b * WIN + (size_t)(tb + t) * IC, child);
    if constexpr (!FIRST) {
#pragma unroll
      for (int c = 0; c < IC; ++c)
        child[c] = child[c] * sScale[t * IC + c] + sShift[t * IC + c];
    }
    float hv[6];
#pragma unroll
    for (int o = 0; o < 6; ++o) {
      float a = sB[t * 6 + o];
      const float* wr = &sW[(t * 6 + o) * IC];
#pragma unroll
      for (int j = 0; j < IC; ++j) a += child[j] * wr[j];
      float h = tanh_fast(a);
      hv[o] = h;
      ls[o] += h;
      lq[o] += h * h;
    }
    TOUT* op = out + (size_t)b * WOUT + (size_t)(tb + t) * 6;
    if constexpr (sizeof(TOUT) == 2) {
      unsigned int* oi = (unsigned int*)op;
#pragma unroll
      for (int i2 = 0; i2 < 3; ++i2)
        oi[i2] = (unsigned int)f2bf(hv[2 * i2]) |
                 ((unsigned int)f2bf(hv[2 * i2 + 1]) << 16);
    } else {
#pragma unroll
      for (int i2 = 0; i2 < 6; ++i2) op[i2] = hv[i2];
    }
  }

  // stats: stage per-thread partials, reduce over NB bsubs, 1 atomic each
#pragma unroll
  for (int j = 0; j < 6; ++j) {
    sRed[threadIdx.x][j] = ls[j];
    sRed[threadIdx.x][6 + j] = lq[j];
  }
  __syncthreads();
  for (int i = threadIdx.x; i < TG * 6; i += 256) {
    int tt = i / 6, o = i % 6;
    float s = 0.0f, q = 0.0f;
    for (int nb = 0; nb < NB; ++nb) {
      s += sRed[nb * TG + tt][o];
      q += sRed[nb * TG + tt][6 + o];
    }
    atomicAdd(&curStats[(tb + tt) * 6 + o], s);
    atomicAdd(&curStats[WOUT + (tb + tt) * 6 + o], q);
  }
}

// ---------------------------------------------------------------------------
// Final: root = BN(h5) -> out(4096x768) = root @ Wf^T + bf
// ---------------------------------------------------------------------------
__global__ __launch_bounds__(256) void final_fc(
    const float* __restrict__ h5, const float* __restrict__ stats5,
    const float* __restrict__ gm5, const float* __restrict__ bt5,
    const float* __restrict__ Wf, const float* __restrict__ bfv,
    float* __restrict__ out) {
  __shared__ float sWf[768 * 6];
  __shared__ float sbf[768];
  __shared__ float sRoot[8][6];
  const int tid = threadIdx.x;
  for (int i = tid; i < 768 * 6; i += 256) sWf[i] = Wf[i];
  for (int i = tid; i < 768; i += 256) sbf[i] = bfv[i];
  const int b0 = blockIdx.x * 8;
  if (tid < 48) {
    int bb = tid / 6, o = tid % 6;
    float mu = stats5[o] * (1.0f / 4096.0f);
    float var = stats5[6 + o] * (1.0f / 4096.0f) - mu * mu;
    float sc = rsqrtf(var + 1e-5f) * gm5[o];
    sRoot[bb][o] = (h5[(size_t)(b0 + bb) * 6 + o] - mu) * sc + bt5[o];
  }
  __syncthreads();
#pragma unroll
  for (int bb = 0; bb < 8; ++bb) {
    float r0 = sRoot[bb][0], r1 = sRoot[bb][1], r2 = sRoot[bb][2];
    float r3 = sRoot[bb][3], r4 = sRoot[bb][4], r5 = sRoot[bb][5];
    for (int d = tid; d < 768; d += 256) {
      const float* wr = &sWf[d * 6];
      float a = sbf[d] + r0 * wr[0] + r1 * wr[1] + r2 * wr[2] +
                r3 * wr[3] + r4 * wr[4] + r5 * wr[5];
      out[(size_t)(b0 + bb) * 768 + d] = a;
    }
  }
}

// ---------------------------------------------------------------------------
// launch
// ---------------------------------------------------------------------------
extern "C" void kernel_launch(void* const* d_in, const int* in_sizes, int n_in,
                              void* d_out, int out_size, void* d_ws,
                              size_t ws_size, hipStream_t stream) {
  const float* x   = (const float*)d_in[0];
  const float* Wg  = (const float*)d_in[1];
  const float* bg  = (const float*)d_in[2];
  const float* W0  = (const float*)d_in[3];
  const float* b0v = (const float*)d_in[4];
  const float* gm0 = (const float*)d_in[5];
  const float* bt0 = (const float*)d_in[6];
  const float* W1  = (const float*)d_in[7];
  const float* b1v = (const float*)d_in[8];
  const float* gm1 = (const float*)d_in[9];
  const float* bt1 = (const float*)d_in[10];
  const float* W2  = (const float*)d_in[11];
  const float* b2v = (const float*)d_in[12];
  const float* gm2 = (const float*)d_in[13];
  const float* bt2 = (const float*)d_in[14];
  const float* W3  = (const float*)d_in[15];
  const float* b3v = (const float*)d_in[16];
  const float* gm3 = (const float*)d_in[17];
  const float* bt3 = (const float*)d_in[18];
  const float* W4  = (const float*)d_in[19];
  const float* b4v = (const float*)d_in[20];
  const float* gm4 = (const float*)d_in[21];
  const float* bt4 = (const float*)d_in[22];
  const float* W5  = (const float*)d_in[23];
  const float* b5v = (const float*)d_in[24];
  const float* gm5 = (const float*)d_in[25];
  const float* bt5 = (const float*)d_in[26];
  const float* Wf  = (const float*)d_in[27];
  const float* bfv = (const float*)d_in[28];

  char* ws = (char*)d_ws;
  unsigned short* Xb  = (unsigned short*)(ws + 0);            // 24,641,536
  unsigned short* Wgb = (unsigned short*)(ws + 24641536ULL);  // 98,566,144
  unsigned short* G   = (unsigned short*)(ws + 123207680ULL); // 134,217,728
  unsigned short* h0  = (unsigned short*)(ws + 257425408ULL); // 100,663,296
  unsigned short* h1  = (unsigned short*)(ws + 358088704ULL); // 25,165,824
  unsigned short* h2  = (unsigned short*)(ws + 383254528ULL); //  6,291,456
  float* h3 = (float*)(ws + 389545984ULL);                    //  3,145,728
  float* h4 = (float*)(ws + 392691712ULL);                    //    786,432
  float* h5 = (float*)(ws + 393478144ULL);                    //     98,304
  float* stats = (float*)(ws + 393576448ULL);                 //    131,072

  hipMemsetAsync(stats, 0, 131072, stream);

  cvt_all<<<dim3(60160), 256, 0, stream>>>(x, Wg, Xb, Wgb);

  gemm_bt<<<dim3(64, 16), 512, 0, stream>>>(Xb, Wgb, bg, G);

  term_layer<unsigned short, unsigned short, 2048, 8, 64, true>
      <<<dim3(32, 64), 256, 0, stream>>>(G, nullptr, nullptr, nullptr, W0, b0v,
                                         h0, stats + 0);
  term_layer<unsigned short, unsigned short, 512, 24, 32, false>
      <<<dim3(16, 64), 256, 0, stream>>>(h0, stats + 0, gm0, bt0, W1, b1v, h1,
                                         stats + 24576);
  term_layer<unsigned short, unsigned short, 128, 24, 32, false>
      <<<dim3(4, 128), 256, 0, stream>>>(h1, stats + 24576, gm1, bt1, W2, b2v,
                                         h2, stats + 30720);
  term_layer<unsigned short, float, 32, 24, 32, false>
      <<<dim3(1, 128), 256, 0, stream>>>(h2, stats + 30720, gm2, bt2, W3, b3v,
                                         h3, stats + 32256);
  term_layer<float, float, 8, 24, 8, false>
      <<<dim3(1, 64), 256, 0, stream>>>(h3, stats + 32256, gm3, bt3, W4, b4v,
                                        h4, stats + 32640);
  term_layer<float, float, 1, 48, 1, false>
      <<<dim3(1, 16), 256, 0, stream>>>(h4, stats + 32640, gm4, bt4, W5, b5v,
                                        h5, stats + 32736);

  final_fc<<<dim3(512), 256, 0, stream>>>(h5, stats + 32736, gm5, bt5, Wf, bfv,
                                          (float*)d_out);
}

// Round 2
// 852.656 us; speedup vs baseline: 1.0908x; 1.0806x over previous
//
#include <hip/hip_runtime.h>

// ---------------------------------------------------------------------------
// DrugCell-style VNN. R6: gemm_bt = m201-style 256x256 8-phase pipeline.
// BK=64, 47 K-steps, 8 waves (2Mx4N, per-wave frags straddle both halves).
// Per K-step: 4 quadrant-phases {ds_read frags; stage 1 half-tile; [vmcnt];
// barrier; lgkm(0); setprio(1); 16 MFMA; setprio(0); barrier}.
// Slot liveness: quadrants (m0n0,m1n0,m1n1,m0n1) free B0@p2,A1@p3,A0/B1@p4;
// stages p1:A0(s+1) p2:B1(s+1) p3:B0(s+2) p4:A1(s+2) each hit the slot freed
// at end of the previous phase. vmcnt(4) at p4 retires next step's 4 halves.
// ---------------------------------------------------------------------------

typedef float f32x4 __attribute__((ext_vector_type(4)));
typedef __bf16 bf16x8 __attribute__((ext_vector_type(8)));

#define GL2LDS(g, l)                                                          \
  __builtin_amdgcn_global_load_lds(                                           \
      (__attribute__((address_space(1))) void*)(g),                           \
      (__attribute__((address_space(3))) void*)(l), 16, 0, 0)

__device__ __forceinline__ unsigned short f2bf(float f) {
  unsigned int u = __float_as_uint(f);
  u = u + 0x7fffu + ((u >> 16) & 1u);   // round-to-nearest-even
  return (unsigned short)(u >> 16);
}

__device__ __forceinline__ float bf2f(unsigned int lo16) {
  return __uint_as_float(lo16 << 16);
}

__device__ __forceinline__ float tanh_fast(float x) {
  float e = __expf(2.0f * x);
  return 1.0f - __fdividef(2.0f, e + 1.0f);
}

// ---------------------------------------------------------------------------
// fp32 -> bf16 conversion of x and Wg in one launch
// ---------------------------------------------------------------------------
__global__ __launch_bounds__(256) void cvt_all(
    const float* __restrict__ x, const float* __restrict__ wg,
    unsigned short* __restrict__ xb, unsigned short* __restrict__ wgb) {
  constexpr int NX = 12320768 / 4;
  constexpr int NW = 49283072 / 4;
  int i = blockIdx.x * 256 + threadIdx.x;
  const float* src;
  unsigned short* dst;
  int j;
  if (i < NX) {
    src = x; dst = xb; j = i;
  } else {
    j = i - NX;
    if (j >= NW) return;
    src = wg; dst = wgb;
  }
  float4 v = ((const float4*)src)[j];
  ushort4 o;
  o.x = f2bf(v.x); o.y = f2bf(v.y); o.z = f2bf(v.z); o.w = f2bf(v.w);
  ((ushort4*)dst)[j] = o;
}

// ---------------------------------------------------------------------------
// bf16 GEMM: C(4096x16384) = A(MxK)*B(NxK)^T + bias[n], K=3008.
// LDS half-tile slot = 128 rows x 64 cols bf16 (16 KB). Row r, k-chunk c
// (8 elems) stored at chunk (c ^ (r&7)) -> conflict-free ds_read_b128 and
// linear gl2lds dest (source pre-swizzled per lane).
// A slots: [parity][half] at ((par<<1|h)*8192) elems; B at +32768.
// ---------------------------------------------------------------------------
__global__ __launch_bounds__(512, 2) void gemm_bt(
    const unsigned short* __restrict__ A, const unsigned short* __restrict__ Bm,
    const float* __restrict__ bias, unsigned short* __restrict__ C) {
  constexpr int N = 16384, K = 3008;
  __shared__ unsigned short lds[65536];  // 128 KiB
  const int tid = threadIdx.x;
  const int w = tid >> 6, l = tid & 63;
  const int m0 = blockIdx.y * 256, n0 = blockIdx.x * 256;

  // ---- staging: per-lane pre-swizzled global source, wave-uniform LDS base
  const int r0 = tid >> 3;                 // 0..63
  const int c0 = (tid & 7) ^ (r0 & 7);
  const unsigned short* gA = A + (size_t)(m0 + r0) * K + c0 * 8;
  const unsigned short* gB = Bm + (size_t)(n0 + r0) * K + c0 * 8;
  const int wbase = w * 512;               // elems; HW adds lane*16B

#define ASLOT(par, h) (lds + ((((par) << 1) | (h)) * 8192))
#define BSLOT(par, h) (lds + 32768 + ((((par) << 1) | (h)) * 8192))

#define STAGEA(par, h, kofE)                                                  \
  do {                                                                        \
    unsigned short* d_ = ASLOT(par, h) + wbase;                               \
    GL2LDS(gA + (size_t)((h) * 128) * K + (kofE), d_);                        \
    GL2LDS(gA + (size_t)((h) * 128 + 64) * K + (kofE), d_ + 4096);            \
  } while (0)
#define STAGEB(par, h, kofE)                                                  \
  do {                                                                        \
    unsigned short* d_ = BSLOT(par, h) + wbase;                               \
    GL2LDS(gB + (size_t)((h) * 128) * K + (kofE), d_);                        \
    GL2LDS(gB + (size_t)((h) * 128 + 64) * K + (kofE), d_ + 4096);            \
  } while (0)

  // ---- fragment read offsets (elems within a half-tile slot)
  const int quad = l >> 4, lrow = l & 15;
  int aO[2][4], bO[2][2];
#pragma unroll
  for (int f = 0; f < 4; ++f) {
    int ra = (w >> 2) * 64 + f * 16 + lrow;       // 0..127
#pragma unroll
    for (int kk = 0; kk < 2; ++kk)
      aO[kk][f] = ra * 64 + (((kk * 4 + quad) ^ (ra & 7)) * 8);
  }
#pragma unroll
  for (int n = 0; n < 2; ++n) {
    int rb = (w & 3) * 32 + n * 16 + lrow;        // 0..127
#pragma unroll
    for (int kk = 0; kk < 2; ++kk)
      bO[kk][n] = rb * 64 + (((kk * 4 + quad) ^ (rb & 7)) * 8);
  }

  f32x4 acc[8][4];
#pragma unroll
  for (int i = 0; i < 8; ++i)
#pragma unroll
    for (int j = 0; j < 4; ++j) acc[i][j] = (f32x4)0.0f;
  bf16x8 av[4][2], bv[2][2];

#define VM4 asm volatile("s_waitcnt vmcnt(4)" ::: "memory")
#define VM0 asm volatile("s_waitcnt vmcnt(0)" ::: "memory")
#define NOVM ((void)0)

#define PHASE(par, mh, nh, LA, LB, STG, VMSTMT)                               \
  {                                                                           \
    if (LA) {                                                                 \
      _Pragma("unroll") for (int f = 0; f < 4; ++f) {                         \
        av[f][0] = *(const bf16x8*)(ASLOT(par, mh) + aO[0][f]);               \
        av[f][1] = *(const bf16x8*)(ASLOT(par, mh) + aO[1][f]);               \
      }                                                                       \
    }                                                                         \
    if (LB) {                                                                 \
      _Pragma("unroll") for (int n = 0; n < 2; ++n) {                         \
        bv[n][0] = *(const bf16x8*)(BSLOT(par, nh) + bO[0][n]);               \
        bv[n][1] = *(const bf16x8*)(BSLOT(par, nh) + bO[1][n]);               \
      }                                                                       \
    }                                                                         \
    STG;                                                                      \
    VMSTMT;                                                                   \
    __builtin_amdgcn_s_barrier();                                             \
    asm volatile("s_waitcnt lgkmcnt(0)" ::: "memory");                        \
    __builtin_amdgcn_sched_barrier(0);                                        \
    __builtin_amdgcn_s_setprio(1);                                            \
    _Pragma("unroll") for (int f = 0; f < 4; ++f)                             \
      _Pragma("unroll") for (int n = 0; n < 2; ++n) {                         \
        acc[(mh) * 4 + f][(nh) * 2 + n] =                                     \
            __builtin_amdgcn_mfma_f32_16x16x32_bf16(                          \
                av[f][0], bv[n][0], acc[(mh) * 4 + f][(nh) * 2 + n], 0, 0, 0);\
        acc[(mh) * 4 + f][(nh) * 2 + n] =                                     \
            __builtin_amdgcn_mfma_f32_16x16x32_bf16(                          \
                av[f][1], bv[n][1], acc[(mh) * 4 + f][(nh) * 2 + n], 0, 0, 0);\
      }                                                                       \
    __builtin_amdgcn_s_setprio(0);                                            \
    __builtin_amdgcn_s_barrier();                                             \
  }

#define STEP(par, S1, S2, VMSTMT)                                             \
  PHASE(par, 0, 0, true, true, if (S1) STAGEA((par) ^ 1, 0, kof + 64), NOVM); \
  PHASE(par, 1, 0, true, false, if (S1) STAGEB((par) ^ 1, 1, kof + 64), NOVM);\
  PHASE(par, 1, 1, false, true, if (S2) STAGEB(par, 0, kof + 128), NOVM);     \
  PHASE(par, 0, 1, true, false, if (S2) STAGEA(par, 1, kof + 128), VMSTMT);   \
  kof += 64;

  int kof = 0;
  // prologue: step0's 4 halves + B0(1), A1(1)  (12 loads; vmcnt(4) retires
  // the 8 step-0 loads, leaving B0(1),A1(1) in flight = steady invariant)
  STAGEA(0, 0, 0); STAGEB(0, 0, 0); STAGEA(0, 1, 0); STAGEB(0, 1, 0);
  STAGEB(1, 0, 64); STAGEA(1, 1, 64);
  VM4;
  __builtin_amdgcn_s_barrier();

  for (int it = 0; it < 22; ++it) {  // s = 0..43
    STEP(0, true, true, VM4);
    STEP(1, true, true, VM4);
  }
  STEP(0, true, true, VM4);    // s=44: stages 45 full, 46 halves B0/A1
  STEP(1, true, false, VM0);   // s=45: stages A0(46),B1(46); drain all
  STEP(0, false, false, NOVM); // s=46: compute only

#undef STEP
#undef PHASE
#undef STAGEA
#undef STAGEB
#undef ASLOT
#undef BSLOT

  // epilogue: C/D layout col=lane&15, row=quad*4+reg
#pragma unroll
  for (int bn = 0; bn < 4; ++bn) {
    int n = n0 + (bn >> 1) * 128 + (w & 3) * 32 + (bn & 1) * 16 + lrow;
    float bnv = bias[n];
#pragma unroll
    for (int F = 0; F < 8; ++F) {
      int mbase = m0 + (F >> 2) * 128 + (w >> 2) * 64 + (F & 3) * 16 + quad * 4;
#pragma unroll
      for (int r = 0; r < 4; ++r) {
        C[(size_t)(mbase + r) * N + n] = f2bf(acc[F][bn][r] + bnv);
      }
    }
  }
}

// ---------------------------------------------------------------------------
// row loaders (term-slice of IC elements)
// ---------------------------------------------------------------------------
template <int IC>
__device__ __forceinline__ void load_row(const unsigned short* p, float* d) {
  static_assert(IC % 8 == 0, "");
#pragma unroll
  for (int i = 0; i < IC / 8; ++i) {
    uint4 u = *(const uint4*)(p + i * 8);
    d[i * 8 + 0] = bf2f(u.x & 0xffffu); d[i * 8 + 1] = bf2f(u.x >> 16);
    d[i * 8 + 2] = bf2f(u.y & 0xffffu); d[i * 8 + 3] = bf2f(u.y >> 16);
    d[i * 8 + 4] = bf2f(u.z & 0xffffu); d[i * 8 + 5] = bf2f(u.z >> 16);
    d[i * 8 + 6] = bf2f(u.w & 0xffffu); d[i * 8 + 7] = bf2f(u.w >> 16);
  }
}
template <int IC>
__device__ __forceinline__ void load_row(const float* p, float* d) {
  static_assert(IC % 4 == 0, "");
#pragma unroll
  for (int i = 0; i < IC / 4; ++i) {
    float4 v = *(const float4*)(p + i * 4);
    d[i * 4 + 0] = v.x; d[i * 4 + 1] = v.y;
    d[i * 4 + 2] = v.z; d[i * 4 + 3] = v.w;
  }
}

// ---------------------------------------------------------------------------
// Term layer: block = TG terms x (4096/gridDim.y) b's; tid = bsub*TG + t.
// Wave lanes cover consecutive terms -> contiguous row-slice reads.
// ---------------------------------------------------------------------------
template <typename TIN, typename TOUT, int T, int IC, int TG, bool FIRST>
__global__ __launch_bounds__(256) void term_layer(
    const TIN* __restrict__ in, const float* __restrict__ prevStats,
    const float* __restrict__ prevGm, const float* __restrict__ prevBt,
    const float* __restrict__ W, const float* __restrict__ bvec,
    TOUT* __restrict__ out, float* __restrict__ curStats) {
  constexpr int WIN = T * IC;
  constexpr int WOUT = T * 6;
  constexpr int NB = 256 / TG;
  const int tb = blockIdx.x * TG;
  const int t = threadIdx.x & (TG - 1);
  const int bsub = threadIdx.x / TG;

  __shared__ float sW[TG * 6 * IC];
  __shared__ float sB[TG * 6];
  __shared__ float sScale[FIRST ? 1 : TG * IC];
  __shared__ float sShift[FIRST ? 1 : TG * IC];
  __shared__ float sRed[256][13];  // 13: odd stride, conflict-free

  for (int i = threadIdx.x; i < TG * 6 * IC; i += 256)
    sW[i] = W[(size_t)tb * 6 * IC + i];
  for (int i = threadIdx.x; i < TG * 6; i += 256) sB[i] = bvec[tb * 6 + i];
  if constexpr (!FIRST) {
    for (int i = threadIdx.x; i < TG * IC; i += 256) {
      int gc = tb * IC + i;
      float mu = prevStats[gc] * (1.0f / 4096.0f);
      float var = prevStats[WIN + gc] * (1.0f / 4096.0f) - mu * mu;
      float sc = rsqrtf(var + 1e-5f) * prevGm[gc];
      sScale[i] = sc;
      sShift[i] = prevBt[gc] - mu * sc;
    }
  }
  __syncthreads();

  float ls[6], lq[6];
#pragma unroll
  for (int i = 0; i < 6; ++i) { ls[i] = 0.0f; lq[i] = 0.0f; }

  const int bchunk = 4096 / gridDim.y;
  const int rows = bchunk / NB;
  const int b0 = blockIdx.y * bchunk + bsub * rows;
  for (int i = 0; i < rows; ++i) {
    int b = b0 + i;
    float child[IC];
    load_row<IC>(in + (size_t)b * WIN + (size_t)(tb + t) * IC, child);
    if constexpr (!FIRST) {
#pragma unroll
      for (int c = 0; c < IC; ++c)
        child[c] = child[c] * sScale[t * IC + c] + sShift[t * IC + c];
    }
    float hv[6];
#pragma unroll
    for (int o = 0; o < 6; ++o) {
      float a = sB[t * 6 + o];
      const float* wr = &sW[(t * 6 + o) * IC];
#pragma unroll
      for (int j = 0; j < IC; ++j) a += child[j] * wr[j];
      float h = tanh_fast(a);
      hv[o] = h;
      ls[o] += h;
      lq[o] += h * h;
    }
    TOUT* op = out + (size_t)b * WOUT + (size_t)(tb + t) * 6;
    if constexpr (sizeof(TOUT) == 2) {
      unsigned int* oi = (unsigned int*)op;
#pragma unroll
      for (int i2 = 0; i2 < 3; ++i2)
        oi[i2] = (unsigned int)f2bf(hv[2 * i2]) |
                 ((unsigned int)f2bf(hv[2 * i2 + 1]) << 16);
    } else {
#pragma unroll
      for (int i2 = 0; i2 < 6; ++i2) op[i2] = hv[i2];
    }
  }

  // stats: stage per-thread partials, reduce over NB bsubs, 1 atomic each
#pragma unroll
  for (int j = 0; j < 6; ++j) {
    sRed[threadIdx.x][j] = ls[j];
    sRed[threadIdx.x][6 + j] = lq[j];
  }
  __syncthreads();
  for (int i = threadIdx.x; i < TG * 6; i += 256) {
    int tt = i / 6, o = i % 6;
    float s = 0.0f, q = 0.0f;
    for (int nb = 0; nb < NB; ++nb) {
      s += sRed[nb * TG + tt][o];
      q += sRed[nb * TG + tt][6 + o];
    }
    atomicAdd(&curStats[(tb + tt) * 6 + o], s);
    atomicAdd(&curStats[WOUT + (tb + tt) * 6 + o], q);
  }
}

// ---------------------------------------------------------------------------
// Final: root = BN(h5) -> out(4096x768) = root @ Wf^T + bf
// ---------------------------------------------------------------------------
__global__ __launch_bounds__(256) void final_fc(
    const float* __restrict__ h5, const float* __restrict__ stats5,
    const float* __restrict__ gm5, const float* __restrict__ bt5,
    const float* __restrict__ Wf, const float* __restrict__ bfv,
    float* __restrict__ out) {
  __shared__ float sWf[768 * 6];
  __shared__ float sbf[768];
  __shared__ float sRoot[8][6];
  const int tid = threadIdx.x;
  for (int i = tid; i < 768 * 6; i += 256) sWf[i] = Wf[i];
  for (int i = tid; i < 768; i += 256) sbf[i] = bfv[i];
  const int b0 = blockIdx.x * 8;
  if (tid < 48) {
    int bb = tid / 6, o = tid % 6;
    float mu = stats5[o] * (1.0f / 4096.0f);
    float var = stats5[6 + o] * (1.0f / 4096.0f) - mu * mu;
    float sc = rsqrtf(var + 1e-5f) * gm5[o];
    sRoot[bb][o] = (h5[(size_t)(b0 + bb) * 6 + o] - mu) * sc + bt5[o];
  }
  __syncthreads();
#pragma unroll
  for (int bb = 0; bb < 8; ++bb) {
    float r0 = sRoot[bb][0], r1 = sRoot[bb][1], r2 = sRoot[bb][2];
    float r3 = sRoot[bb][3], r4 = sRoot[bb][4], r5 = sRoot[bb][5];
    for (int d = tid; d < 768; d += 256) {
      const float* wr = &sWf[d * 6];
      float a = sbf[d] + r0 * wr[0] + r1 * wr[1] + r2 * wr[2] +
                r3 * wr[3] + r4 * wr[4] + r5 * wr[5];
      out[(size_t)(b0 + bb) * 768 + d] = a;
    }
  }
}

// ---------------------------------------------------------------------------
// launch
// ---------------------------------------------------------------------------
extern "C" void kernel_launch(void* const* d_in, const int* in_sizes, int n_in,
                              void* d_out, int out_size, void* d_ws,
                              size_t ws_size, hipStream_t stream) {
  const float* x   = (const float*)d_in[0];
  const float* Wg  = (const float*)d_in[1];
  const float* bg  = (const float*)d_in[2];
  const float* W0  = (const float*)d_in[3];
  const float* b0v = (const float*)d_in[4];
  const float* gm0 = (const float*)d_in[5];
  const float* bt0 = (const float*)d_in[6];
  const float* W1  = (const float*)d_in[7];
  const float* b1v = (const float*)d_in[8];
  const float* gm1 = (const float*)d_in[9];
  const float* bt1 = (const float*)d_in[10];
  const float* W2  = (const float*)d_in[11];
  const float* b2v = (const float*)d_in[12];
  const float* gm2 = (const float*)d_in[13];
  const float* bt2 = (const float*)d_in[14];
  const float* W3  = (const float*)d_in[15];
  const float* b3v = (const float*)d_in[16];
  const float* gm3 = (const float*)d_in[17];
  const float* bt3 = (const float*)d_in[18];
  const float* W4  = (const float*)d_in[19];
  const float* b4v = (const float*)d_in[20];
  const float* gm4 = (const float*)d_in[21];
  const float* bt4 = (const float*)d_in[22];
  const float* W5  = (const float*)d_in[23];
  const float* b5v = (const float*)d_in[24];
  const float* gm5 = (const float*)d_in[25];
  const float* bt5 = (const float*)d_in[26];
  const float* Wf  = (const float*)d_in[27];
  const float* bfv = (const float*)d_in[28];

  char* ws = (char*)d_ws;
  unsigned short* Xb  = (unsigned short*)(ws + 0);            // 24,641,536
  unsigned short* Wgb = (unsigned short*)(ws + 24641536ULL);  // 98,566,144
  unsigned short* G   = (unsigned short*)(ws + 123207680ULL); // 134,217,728
  unsigned short* h0  = (unsigned short*)(ws + 257425408ULL); // 100,663,296
  unsigned short* h1  = (unsigned short*)(ws + 358088704ULL); // 25,165,824
  unsigned short* h2  = (unsigned short*)(ws + 383254528ULL); //  6,291,456
  float* h3 = (float*)(ws + 389545984ULL);                    //  3,145,728
  float* h4 = (float*)(ws + 392691712ULL);                    //    786,432
  float* h5 = (float*)(ws + 393478144ULL);                    //     98,304
  float* stats = (float*)(ws + 393576448ULL);                 //    131,072

  hipMemsetAsync(stats, 0, 131072, stream);

  cvt_all<<<dim3(60160), 256, 0, stream>>>(x, Wg, Xb, Wgb);

  gemm_bt<<<dim3(64, 16), 512, 0, stream>>>(Xb, Wgb, bg, G);

  term_layer<unsigned short, unsigned short, 2048, 8, 64, true>
      <<<dim3(32, 64), 256, 0, stream>>>(G, nullptr, nullptr, nullptr, W0, b0v,
                                         h0, stats + 0);
  term_layer<unsigned short, unsigned short, 512, 24, 32, false>
      <<<dim3(16, 64), 256, 0, stream>>>(h0, stats + 0, gm0, bt0, W1, b1v, h1,
                                         stats + 24576);
  term_layer<unsigned short, unsigned short, 128, 24, 32, false>
      <<<dim3(4, 128), 256, 0, stream>>>(h1, stats + 24576, gm1, bt1, W2, b2v,
                                         h2, stats + 30720);
  term_layer<unsigned short, float, 32, 24, 32, false>
      <<<dim3(1, 128), 256, 0, stream>>>(h2, stats + 30720, gm2, bt2, W3, b3v,
                                         h3, stats + 32256);
  term_layer<float, float, 8, 24, 8, false>
      <<<dim3(1, 64), 256, 0, stream>>>(h3, stats + 32256, gm3, bt3, W4, b4v,
                                        h4, stats + 32640);
  term_layer<float, float, 1, 48, 1, false>
      <<<dim3(1, 16), 256, 0, stream>>>(h4, stats + 32640, gm4, bt4, W5, b5v,
                                        h5, stats + 32736);

  final_fc<<<dim3(512), 256, 0, stream>>>(h5, stats + 32736, gm5, bt5, Wf, bfv,
                                          (float*)d_out);
}